// Round 4
// baseline (16035.753 us; speedup 1.0000x reference)
//
#include <hip/hip_runtime.h>

// RIM network, persistent 2-phase-per-step kernel for MI355X (gfx950).
// B=256,T=128,I=128,H=256,M=6,MPG=2,K=16,R=16,NH=4,TASK=32,SENS=96,O=64
//
//  X phase: block = (module xm, 8-row batch chunk xc)
//  Y phase: block = (head ya, module yn, d-half ydh, 64-row chunk yc)
//
// Coherence strategy (round 4): NO fences anywhere. Inter-block data
// (Hpk, Qs, Ks, Vc, aww, hid[m>=4]) uses agent-scope RELAXED atomics =
// cache-bypass write-through/read-through at the coherence point. Weights
// and x use normal cached loads and stay L2-resident the whole kernel
// (rounds 2/3 lost 2x each to per-barrier L2 invalidates). Barrier =
// syncthreads (vmcnt drain) + two-level relaxed counters + relaxed spin.

#define NBLK 192
#define T_STEPS 128

typedef __attribute__((ext_vector_type(8))) short bf16x8;
typedef __attribute__((ext_vector_type(4))) float f32x4;

__device__ __forceinline__ unsigned short f2bf(float f){
  unsigned u = __float_as_uint(f);
  u += 0x7FFFu + ((u >> 16) & 1u);           // RNE
  return (unsigned short)(u >> 16);
}
__device__ __forceinline__ float bf2f(unsigned short h){
  return __uint_as_float(((unsigned)h) << 16);
}
__device__ __forceinline__ bf16x8 bzero8(){
  bf16x8 v;
#pragma unroll
  for (int i = 0; i < 8; ++i) v[i] = 0;
  return v;
}

// agent-scope coherent (cache-bypass) access helpers
__device__ __forceinline__ float ld_coh(const float* a){
  return __hip_atomic_load(const_cast<float*>(a), __ATOMIC_RELAXED, __HIP_MEMORY_SCOPE_AGENT);
}
__device__ __forceinline__ unsigned long long ld_coh8(const void* a){
  return __hip_atomic_load((unsigned long long*)a, __ATOMIC_RELAXED, __HIP_MEMORY_SCOPE_AGENT);
}
__device__ __forceinline__ void st_coh(float* a, float v){
  __hip_atomic_store(a, v, __ATOMIC_RELAXED, __HIP_MEMORY_SCOPE_AGENT);
}
__device__ __forceinline__ void st_cohu(unsigned* a, unsigned v){
  __hip_atomic_store(a, v, __ATOMIC_RELAXED, __HIP_MEMORY_SCOPE_AGENT);
}

struct Params {
  const float *x, *Wt, *Wsn, *Wip, *bip, *U, *Vlr, *bias, *WQ, *WK, *WV, *Wout, *bout;
  float *out0, *hid, *ain, *acm, *aww;
  unsigned short *WVhi, *WVlo, *WQKhi, *WQKlo, *Wfshi, *Wfslo, *Wins, *Wouthi, *Woutlo;
  unsigned *Hpk;
  float *Qs, *Ks, *Vc;
  unsigned *bar;
};

// ---------------- prep: fold W_in @ Wip (fp32), swizzle into B-frag layout (hi/lo)
__global__ void prep_fold(Params p){
  int bid = blockIdx.x; int d = threadIdx.x;   // 256 blocks x 256 threads
  int m, i;
  if (bid < 32)       { m = 0; i = bid; }
  else if (bid < 64)  { m = 1; i = bid - 32; }
  else if (bid < 160) { m = 2; i = bid - 64; }
  else                { m = 3; i = bid - 160; }
  const float* wrow = (m < 2) ? (p.Wt + (m*32 + i)*256) : (p.Wsn + ((m-2)*96 + i)*256);
  const float* wip  = p.Wip + (long)m*256*256;
  float acc = 0.f;
  for (int h = 0; h < 256; ++h) acc += wrow[h] * wip[h*256 + d];
  int kt = i >> 5, j = i & 7, lane = ((i >> 3) & 3)*16 + (d & 15), nt = d >> 4;
  long off = (((long)(m*3 + kt)*16 + nt)*64 + lane)*8 + j;
  unsigned short hi = f2bf(acc);
  p.Wfshi[off] = hi;
  p.Wfslo[off] = f2bf(acc - bf2f(hi));
  p.Wins[off]  = f2bf(wrow[d]);
}

// ---------------- prep: swizzle W_V, W_Q|W_K, Wout^T into B-frag layout (hi/lo)
__global__ void prep_swz(Params p){
  int bid = blockIdx.x, tid = threadIdx.x;     // 241 blocks x 512 threads
  if (bid < 192){
    int a = bid/48, n = (bid/8)%6, kt = bid%8;
    const float* src = p.WV + ((long)(a*6+n)*256 + kt*32)*256;
    long dstBase = (((long)(a*6+n)*8 + kt)*16)*512;
    for (int e = tid; e < 8192; e += 512){
      int hl = e >> 8, d = e & 255;            // h = kt*32+hl
      float w = src[hl*256 + d];
      unsigned short hi = f2bf(w);
      unsigned short lo = f2bf(w - bf2f(hi));
      int lane = ((hl>>3)&3)*16 + (d&15), j = hl&7, nt = d>>4;
      long off = dstBase + ((long)nt*64 + lane)*8 + j;
      p.WVhi[off] = hi; p.WVlo[off] = lo;
    }
  } else if (bid < 240){
    int q2 = bid - 192; int m = q2/8, kt = q2%8;
    for (int e = tid; e < 4096; e += 512){
      int hl = e >> 7, c = e & 127;            // cols: [Q a0..3 | K a0..3] x16
      int isK = c >> 6, a = (c>>4)&3, q = c&15;
      const float* W = isK ? p.WK : p.WQ;
      float w = W[((long)(a*6+m)*256 + kt*32 + hl)*16 + q];
      int lane = ((hl>>3)&3)*16 + q, j = hl&7, nt = c>>4;
      long off = (((long)(m*8+kt)*8 + nt)*512) + (long)lane*8 + j;
      unsigned short hi = f2bf(w);
      p.WQKhi[off] = hi; p.WQKlo[off] = f2bf(w - bf2f(hi));
    }
  } else {
    for (int e = tid; e < 32768; e += 512){
      int o = e >> 9, kk = e & 511;
      float w = p.Wout[o*512 + kk];
      int kt = kk>>5, j = kk&7, lane = (((kk>>3)&3)<<4) + (o&15), nt = o>>4;
      long off = ((long)(kt*4+nt)*512) + lane*8 + j;
      unsigned short hi = f2bf(w);
      p.Wouthi[off] = hi; p.Woutlo[off] = f2bf(w - bf2f(hi));
    }
  }
}

// ---------------- global barrier: NO cache maintenance. Two-level counters.
// rel = bar[0]; root = bar[32]; leaf(grp) = bar[64 + grp*32]  (one line each)
__device__ __forceinline__ void gbar(unsigned* bar, unsigned ep, int grp){
  __syncthreads();   // compiler emits s_waitcnt vmcnt(0) before s_barrier:
                     // all write-through stores are at the coherence point.
  if (threadIdx.x == 0){
    unsigned old = __hip_atomic_fetch_add(bar + 64 + grp*32, 1u,
                      __ATOMIC_RELAXED, __HIP_MEMORY_SCOPE_AGENT);
    if (old == ep * 24u - 1u){
      unsigned r = __hip_atomic_fetch_add(bar + 32, 1u,
                      __ATOMIC_RELAXED, __HIP_MEMORY_SCOPE_AGENT);
      if (r == ep * 8u - 1u)
        __hip_atomic_store(bar, ep, __ATOMIC_RELAXED, __HIP_MEMORY_SCOPE_AGENT);
    }
    while (__hip_atomic_load(bar, __ATOMIC_RELAXED, __HIP_MEMORY_SCOPE_AGENT) < ep)
      __builtin_amdgcn_s_sleep(2);
  }
  __syncthreads();
}

// ---------------- main persistent kernel
__global__ __launch_bounds__(512) void rim_main(Params p){
  extern __shared__ char smem[];
  unsigned short* ldsW = (unsigned short*)smem;            // 131072 B  W_V slice (hi/lo)
  unsigned short* xs   = (unsigned short*)(smem + 131072); //   2048 B  x hi   [8][128] (xor-swz)
  unsigned short* xsl  = (unsigned short*)(smem + 133120); //   2048 B  x lo
  unsigned short* hs   = (unsigned short*)(smem + 135168); //   4096 B  H_in hi [8][256] (xor-swz)
  unsigned short* hsl  = (unsigned short*)(smem + 139264); //   4096 B  H_in lo
  float* inpS          = (float*)(smem + 143360);          //   8192 B  inp    [8][256] f32
  float* hcS           = (float*)(smem + 151552);          //   8192 B  H_comm [8][256] f32
  float* rS            = (float*)(smem + 159744);          //    512 B  r      [8][16]  f32
  float* awS           = (float*)(smem + 160256);          //    768 B  aw     [4][8][6] f32

  const int tid = threadIdx.x, bid = blockIdx.x;
  const int lane = tid & 63, wv = tid >> 6;
  const int d = tid & 255, g = tid >> 8;

  // X role: all 6 modules of a batch-chunk on the same XCD (bid%8)
  const int xcdX = bid & 7, xslot = bid >> 3;              // slot 0..23
  const int xm = xslot % 6, xci = xslot / 6;               // xci 0..3
  const int xc = xcdX * 4 + xci;                           // 8-row chunk 0..31

  // Y role: the 8 (ya,ydh) blocks sharing an H_in row-slice on the same XCD
  const int xcdY = bid & 7, yslot = bid >> 3;              // 0..23
  const int yg = xcdY + 8 * (yslot >> 3);                  // group 0..23 = (yn,yc)
  const int yi = yslot & 7;
  const int yn = yg % 6, yc = yg / 6;                      // module, 64-row chunk
  const int ydh = yi >> 2, ya = yi & 3;                    // d-half, head
  const int ych = yc * 2 + ydh;                            // 32-row chunk 0..7 (duties)

  // ---- load this block's W_V slice (hi+lo, 128 KB) into LDS, once ----
  for (int it = 0; it < 16; ++it){
    int q = it*8 + wv;                                     // 128 chunks of 1KB
    int kt = q >> 4, ntl = (q >> 1) & 7, pp = q & 1;
    const unsigned short* src = (pp ? p.WVlo : p.WVhi)
        + ((((long)(ya*6 + yn)*8 + kt)*16 + (ydh*8 + ntl))*64)*8;
    ((int4*)(smem + q*1024))[lane] = ((const int4*)src)[lane];
  }
  __syncthreads();

  float hin[4] = {0.f, 0.f, 0.f, 0.f};
  float hc[4];
  float awprev[4] = {0.f, 0.f, 0.f, 0.f};
  unsigned ep = 0;

  for (int t = 0; t <= T_STEPS; ++t){
    // ================= X phase =================
    if (t > 0){
      // stage aw rows (4 heads x 8 rows x 6 n) into LDS via coherent loads
      if (tid < 192){
        int a = tid / 48, rem = tid % 48, k8 = rem / 6, n = rem % 6;
        awS[tid] = ld_coh(p.aww +
            ((((long)a*T_STEPS + (t-1))*256 + (xc*8 + k8))*6 + xm)*6 + n);
      }
      __syncthreads();
#pragma unroll
      for (int k = 0; k < 4; ++k){
        int kb = g*4 + k;
        int b = xc*8 + kb;
        const float* vbase = p.Vc + (long)b*6*256 + d;
        float acc = 0.f;
#pragma unroll
        for (int a = 0; a < 4; ++a){
          const float* vcr = vbase + (long)a*256*6*256;
#pragma unroll
          for (int n = 0; n < 6; ++n)
            acc += awS[(a*8 + kb)*6 + n] * ld_coh(vcr + n*256);
        }
        float hcm = hin[k] + acc;
        hc[k] = hcm;
        long o = ((long)(b*T_STEPS + (t-1))*6 + xm)*256 + d;
        if (xm >= 4) st_coh(&p.hid[o], hcm);   // consumed by out-proj duty
        else         p.hid[o] = hcm;
        p.acm[o] = acc;
      }
    } else {
      hc[0] = hc[1] = hc[2] = hc[3] = 0.f;
    }

    if (t < T_STEPS){
      if (xm >= 4){
#pragma unroll
        for (int k = 0; k < 4; ++k){
          int b = xc*8 + g*4 + k;
          p.ain[((long)(b*T_STEPS + t)*6 + xm)*256 + d] = 0.f;
        }
      }
      // stage x (bf16 hi/lo, xor-swizzled rows) — normal cached loads
      {
#pragma unroll
        for (int h2 = 0; h2 < 2; ++h2){
          int i0 = tid + h2*512;
          int r0 = i0 >> 7, c0 = i0 & 127;
          float v = p.x[((long)(xc*8 + r0)*T_STEPS + t)*128 + c0];
          unsigned short hi = f2bf(v);
          int idx = r0*128 + (c0 ^ ((r0&7)<<3));
          xs[idx]  = hi;
          xsl[idx] = f2bf(v - bf2f(hi));
        }
      }
      __syncthreads();
      // A_in (single bf16) + inp (emu-fp32) via MFMA (modules 0..3)
      if (xm < 4){
        int nkt = (xm < 2) ? 1 : 3;
        int kbase = (xm < 2) ? 96 : 0;
#pragma unroll
        for (int half = 0; half < 2; ++half){
          int nt = wv*2 + half;
          f32x4 cin = {0.f,0.f,0.f,0.f}, cf = {0.f,0.f,0.f,0.f};
          for (int kt = 0; kt < nkt; ++kt){
            bf16x8 ah = bzero8(), al = bzero8();
            int r = lane & 15;
            if (r < 8){
              int kk = kbase + kt*32 + ((lane>>4)<<3);
              int idx = r*128 + (kk ^ ((r&7)<<3));
              ah = *(const bf16x8*)&xs[idx];
              al = *(const bf16x8*)&xsl[idx];
            }
            long boff = (((long)(xm*3 + kt)*16 + nt)*64 + lane)*8;
            bf16x8 bi = *(const bf16x8*)(p.Wins  + boff);
            bf16x8 bh = *(const bf16x8*)(p.Wfshi + boff);
            bf16x8 bl = *(const bf16x8*)(p.Wfslo + boff);
            cin = __builtin_amdgcn_mfma_f32_16x16x32_bf16(ah, bi, cin, 0, 0, 0);
            cf  = __builtin_amdgcn_mfma_f32_16x16x32_bf16(ah, bh, cf , 0, 0, 0);
            cf  = __builtin_amdgcn_mfma_f32_16x16x32_bf16(al, bh, cf , 0, 0, 0);
            cf  = __builtin_amdgcn_mfma_f32_16x16x32_bf16(ah, bl, cf , 0, 0, 0);
          }
          int col = nt*16 + (lane & 15);
#pragma unroll
          for (int i = 0; i < 4; ++i){
            int r = ((lane>>4)<<2) + i;
            if (r < 8){
              int b = xc*8 + r;
              p.ain[((long)(b*T_STEPS + t)*6 + xm)*256 + col] = cin[i];
              inpS[r*256 + col] = cf[i];
            }
          }
        }
      }
      __syncthreads();
      // stage H_comm(t-1) for rec
#pragma unroll
      for (int k = 0; k < 4; ++k) hcS[(g*4 + k)*256 + d] = hc[k];
      __syncthreads();
      // rec part 1: r[b][q] = sum_h Hc[b][h] U[m][h][q]  (fp32)
      {
        int bl = tid >> 6, q = (tid >> 2) & 15, part = tid & 3;
        const float* up = p.U + (long)xm*256*16 + q;
        float s = 0.f;
        int d0 = part*64;
        for (int dd = 0; dd < 64; ++dd) s += hcS[bl*256 + d0 + dd] * up[(d0 + dd)*16];
        s += __shfl_down(s, 1);
        s += __shfl_down(s, 2);
        if (part == 0) rS[bl*16 + q] = s;
      }
      __syncthreads();
      // H_in = tanh(inp + rec + bip + bias); stash packed bf16 hi|lo
#pragma unroll
      for (int k = 0; k < 4; ++k){
        int bl = g*4 + k;
        float pre = p.bip[xm*256 + d] + p.bias[xm*256 + d];
        if (xm < 4) pre += inpS[bl*256 + d];
        const float* vl = p.Vlr + (long)xm*16*256 + d;
#pragma unroll
        for (int q = 0; q < 16; ++q) pre += rS[bl*16 + q] * vl[q*256];
        float h = tanhf(pre);
        hin[k] = h;
        unsigned short hi = f2bf(h);
        unsigned short lo = f2bf(h - bf2f(hi));
        int b = xc*8 + bl;
        st_cohu(&p.Hpk[((long)xm*256 + b)*256 + d], (unsigned)hi | ((unsigned)lo << 16));
        int idx = bl*256 + (d ^ ((bl&7)<<3));
        hs[idx] = hi; hsl[idx] = lo;
      }
      __syncthreads();
      // Q/K via MFMA (emu-fp32): cols = [Q a0..3 | K a0..3] x 16
      {
        int nt = wv;
        f32x4 c = {0.f,0.f,0.f,0.f};
#pragma unroll
        for (int kt = 0; kt < 8; ++kt){
          bf16x8 ah = bzero8(), al = bzero8();
          int r = lane & 15;
          if (r < 8){
            int kk = kt*32 + ((lane>>4)<<3);
            int idx = r*256 + (kk ^ ((r&7)<<3));
            ah = *(const bf16x8*)&hs[idx];
            al = *(const bf16x8*)&hsl[idx];
          }
          long bo = (((long)(xm*8 + kt)*8 + nt)*64 + lane)*8;
          bf16x8 bh = *(const bf16x8*)(p.WQKhi + bo);
          bf16x8 bl = *(const bf16x8*)(p.WQKlo + bo);
          c = __builtin_amdgcn_mfma_f32_16x16x32_bf16(ah, bh, c, 0, 0, 0);
          c = __builtin_amdgcn_mfma_f32_16x16x32_bf16(al, bh, c, 0, 0, 0);
          c = __builtin_amdgcn_mfma_f32_16x16x32_bf16(ah, bl, c, 0, 0, 0);
        }
        float* dst = (nt < 4) ? p.Qs : p.Ks;
        int a = nt & 3, q = lane & 15;
#pragma unroll
        for (int i = 0; i < 4; ++i){
          int r = ((lane>>4)<<2) + i;
          if (r < 8){
            int b = xc*8 + r;
            st_coh(&dst[((long)(a*256 + b)*6 + xm)*16 + q], c[i]);
          }
        }
      }
    }

    gbar(p.bar, ++ep, bid & 7);

    // ================= Y phase =================
    if (t < T_STEPS){
      // Vc = H_in @ W_V, emu-fp32; A-fragments via coherent 8B loads of packed H
      {
        int nt = wv;
        f32x4 C[4];
#pragma unroll
        for (int rt = 0; rt < 4; ++rt) C[rt] = (f32x4){0.f,0.f,0.f,0.f};
#pragma unroll
        for (int kt = 0; kt < 8; ++kt){
          bf16x8 Ah[4], Al[4];
#pragma unroll
          for (int rt = 0; rt < 4; ++rt){
            int b = yc*64 + rt*16 + (lane & 15);
            const unsigned* hp = p.Hpk + ((long)yn*256 + b)*256 + kt*32 + ((lane>>4)<<3);
#pragma unroll
            for (int jj = 0; jj < 4; ++jj){
              unsigned long long u = ld_coh8(hp + jj*2);
              unsigned w0 = (unsigned)u, w1 = (unsigned)(u >> 32);
              Ah[rt][jj*2]   = (short)(w0 & 0xffffu);
              Al[rt][jj*2]   = (short)(w0 >> 16);
              Ah[rt][jj*2+1] = (short)(w1 & 0xffffu);
              Al[rt][jj*2+1] = (short)(w1 >> 16);
            }
          }
          bf16x8 Bh = *(const bf16x8*)&ldsW[(((kt*8 + nt)*2 + 0)*64 + lane)*8];
          bf16x8 Bl = *(const bf16x8*)&ldsW[(((kt*8 + nt)*2 + 1)*64 + lane)*8];
#pragma unroll
          for (int rt = 0; rt < 4; ++rt){
            C[rt] = __builtin_amdgcn_mfma_f32_16x16x32_bf16(Ah[rt], Bh, C[rt], 0, 0, 0);
            C[rt] = __builtin_amdgcn_mfma_f32_16x16x32_bf16(Al[rt], Bh, C[rt], 0, 0, 0);
            C[rt] = __builtin_amdgcn_mfma_f32_16x16x32_bf16(Ah[rt], Bl, C[rt], 0, 0, 0);
          }
        }
        int dcol = ydh*128 + nt*16 + (lane & 15);
#pragma unroll
        for (int rt = 0; rt < 4; ++rt){
#pragma unroll
          for (int i = 0; i < 4; ++i){
            int b = yc*64 + rt*16 + ((lane>>4)<<2) + i;
            st_coh(&p.Vc[((long)(ya*256 + b)*6 + yn)*256 + dcol], C[rt][i]);
          }
        }
      }
      // attention weights (duty: yn==0 blocks); prev kept in registers
      if (yn == 0 && lane < 36){
        int m = lane / 6, n2 = lane % 6;
#pragma unroll
        for (int bb = 0; bb < 4; ++bb){
          int b = ych*32 + wv*4 + bb;
          const float* qp = p.Qs + ((long)(ya*256 + b)*6 + m)*16;
          const float* kp = p.Ks + ((long)(ya*256 + b)*6 + n2)*16;
          float dot = 0.f;
#pragma unroll
          for (int jj = 0; jj < 8; ++jj){
            unsigned long long uq = ld_coh8(qp + jj*2);
            unsigned long long uk = ld_coh8(kp + jj*2);
            dot += __uint_as_float((unsigned)uq) * __uint_as_float((unsigned)uk)
                 + __uint_as_float((unsigned)(uq>>32)) * __uint_as_float((unsigned)(uk>>32));
          }
          float s = 1.f / (1.f + expf(-dot*0.25f));
          if (t > 0) s = 0.5f*s + 0.5f*awprev[bb];
          awprev[bb] = s;
          st_coh(&p.aww[(((long)ya*T_STEPS + t)*256 + b)*36 + m*6 + n2], s);
        }
      }
    }
    // out projection for step t-1 (duty: ya==0,yn==1; emu-fp32, A from p.hid coherent)
    if (t > 0 && ya == 0 && yn == 1){
      int rt = wv >> 2, nt = wv & 3;
      int rb = ych*32;
      f32x4 c = {0.f,0.f,0.f,0.f};
      for (int kt = 0; kt < 16; ++kt){
        int b = rb + rt*16 + (lane & 15);
        int kk = kt*32 + ((lane>>4)<<3);        // 0..511
        int m45 = kk >> 8, dd = kk & 255;
        const float* hp = p.hid + ((long)(b*T_STEPS + (t-1))*6 + 4 + m45)*256 + dd;
        bf16x8 ah, al;
#pragma unroll
        for (int jj = 0; jj < 4; ++jj){
          unsigned long long u = ld_coh8(hp + jj*2);
          float v0 = __uint_as_float((unsigned)u);
          float v1 = __uint_as_float((unsigned)(u >> 32));
          unsigned short h0 = f2bf(v0), h1 = f2bf(v1);
          ah[jj*2]   = (short)h0; al[jj*2]   = (short)f2bf(v0 - bf2f(h0));
          ah[jj*2+1] = (short)h1; al[jj*2+1] = (short)f2bf(v1 - bf2f(h1));
        }
        long bo = ((long)(kt*4 + nt)*512) + (long)lane*8;
        bf16x8 bh = *(const bf16x8*)(p.Wouthi + bo);
        bf16x8 bl = *(const bf16x8*)(p.Woutlo + bo);
        c = __builtin_amdgcn_mfma_f32_16x16x32_bf16(ah, bh, c, 0, 0, 0);
        c = __builtin_amdgcn_mfma_f32_16x16x32_bf16(al, bh, c, 0, 0, 0);
        c = __builtin_amdgcn_mfma_f32_16x16x32_bf16(ah, bl, c, 0, 0, 0);
      }
      int o = nt*16 + (lane & 15);
      float bo = p.bout[o];
#pragma unroll
      for (int i = 0; i < 4; ++i){
        int b = rb + rt*16 + ((lane>>4)<<2) + i;
        p.out0[((long)b*T_STEPS + (t-1))*64 + o] = c[i] + bo;
      }
    }

    if (t < T_STEPS) gbar(p.bar, ++ep, bid & 7);
  }
}

extern "C" void kernel_launch(void* const* d_in, const int* in_sizes, int n_in,
                              void* d_out, int out_size, void* d_ws, size_t ws_size,
                              hipStream_t stream) {
  (void)in_sizes; (void)n_in; (void)out_size;
  if (ws_size < 16451584) return;

  Params p;
  p.x    = (const float*)d_in[0];
  p.Wt   = (const float*)d_in[1];
  p.Wsn  = (const float*)d_in[2];
  p.Wip  = (const float*)d_in[3];
  p.bip  = (const float*)d_in[4];
  p.U    = (const float*)d_in[5];
  p.Vlr  = (const float*)d_in[6];
  p.bias = (const float*)d_in[7];
  p.WQ   = (const float*)d_in[8];
  p.WK   = (const float*)d_in[9];
  p.WV   = (const float*)d_in[10];
  p.Wout = (const float*)d_in[11];
  p.bout = (const float*)d_in[12];

  float* out = (float*)d_out;
  p.out0 = out;                    // (B,T,O)
  p.hid  = out + 2097152;          // (B,T,M,H)
  p.ain  = out + 52428800;         // (B,T,M,H)
  p.acm  = out + 102760448;        // (B,T,M,H)
  p.aww  = out + 153092096;        // (NH,T,B,M,M)

  char* ws = (char*)d_ws;
  p.bar    = (unsigned*)ws;                         //        0     (2048 B)
  p.WVhi   = (unsigned short*)(ws + 2048);          //  3145728
  p.WVlo   = (unsigned short*)(ws + 3147776);       //  3145728
  p.WQKhi  = (unsigned short*)(ws + 6293504);       //   393216
  p.WQKlo  = (unsigned short*)(ws + 6686720);       //   393216
  p.Wfshi  = (unsigned short*)(ws + 7079936);       //   196608
  p.Wfslo  = (unsigned short*)(ws + 7276544);       //   196608
  p.Wins   = (unsigned short*)(ws + 7473152);       //   196608
  p.Wouthi = (unsigned short*)(ws + 7669760);       //    65536
  p.Woutlo = (unsigned short*)(ws + 7735296);       //    65536
  p.Hpk    = (unsigned*)(ws + 7800832);             //  1572864
  p.Qs     = (float*)(ws + 9373696);                //   393216
  p.Ks     = (float*)(ws + 9766912);                //   393216
  p.Vc     = (float*)(ws + 10160128);               //  6291456 -> 16451584

  hipMemsetAsync(d_ws, 0, 2048, stream);
  hipLaunchKernelGGL(prep_fold, dim3(256), dim3(256), 0, stream, p);
  hipLaunchKernelGGL(prep_swz,  dim3(241), dim3(512), 0, stream, p);

  hipFuncSetAttribute((const void*)rim_main,
                      hipFuncAttributeMaxDynamicSharedMemorySize, 161024);
  hipLaunchKernelGGL(rim_main, dim3(NBLK), dim3(512), 161024, stream, p);
}

// Round 8
// 9404.305 us; speedup vs baseline: 1.7052x; 1.7052x over previous
//
#include <hip/hip_runtime.h>

// RIM network, persistent XCD-local kernel for MI355X (gfx950).
// B=256,T=128,I=128,H=256,M=6,MPG=2,K=16,R=16,NH=4,TASK=32,SENS=96,O=64
//
// Round-8 = round-6 structure (deterministic groups grp=bid&7, cooperative
// launch, verified XCD locality -> LOC fast path / agent-atomic fallback)
// plus: (1) restored 3rd emu product Ah*Bl in Vc (W_V lo-plane read from
// global/L2, immutable weights => plain cached loads); (2) Q/K stored bf16;
// (3) Hpk retiled [m][kt][b][32] so Vc A-frag wave reads are dense 2KB
// windows instead of 16B-at-1KB-stride (8x L2 over-fetch).

#define T_STEPS 128
#define NBLK 256

typedef __attribute__((ext_vector_type(8))) short bf16x8;
typedef __attribute__((ext_vector_type(4))) float f32x4;
typedef __attribute__((ext_vector_type(4))) unsigned u32x4;

__device__ __forceinline__ unsigned short f2bf(float f){
  unsigned u = __float_as_uint(f);
  u += 0x7FFFu + ((u >> 16) & 1u);           // RNE
  return (unsigned short)(u >> 16);
}
__device__ __forceinline__ float bf2f(unsigned short h){
  return __uint_as_float(((unsigned)h) << 16);
}
__device__ __forceinline__ bf16x8 bzero8(){
  bf16x8 v;
#pragma unroll
  for (int i = 0; i < 8; ++i) v[i] = 0;
  return v;
}

// ---- shared-data access, templated on XCD-locality ----
template<bool LOC>
__device__ __forceinline__ void ld4x(const void* a, u32x4& v){
  if constexpr (LOC){
    asm volatile("global_load_dwordx4 %0, %1, off sc0" : "=v"(v) : "v"(a));
  } else {
    unsigned long long u0 = __hip_atomic_load((const unsigned long long*)a,
                              __ATOMIC_RELAXED, __HIP_MEMORY_SCOPE_AGENT);
    unsigned long long u1 = __hip_atomic_load((const unsigned long long*)a + 1,
                              __ATOMIC_RELAXED, __HIP_MEMORY_SCOPE_AGENT);
    v[0]=(unsigned)u0; v[1]=(unsigned)(u0>>32);
    v[2]=(unsigned)u1; v[3]=(unsigned)(u1>>32);
  }
}
__device__ __forceinline__ void vmwait(){
  asm volatile("s_waitcnt vmcnt(0)" ::: "memory");
  __builtin_amdgcn_sched_barrier(0);
}
template<bool LOC>
__device__ __forceinline__ void stf(float* a, float v){
  if constexpr (LOC) *a = v;
  else __hip_atomic_store(a, v, __ATOMIC_RELAXED, __HIP_MEMORY_SCOPE_AGENT);
}
template<bool LOC>
__device__ __forceinline__ void stu(unsigned* a, unsigned v){
  if constexpr (LOC) *a = v;
  else __hip_atomic_store(a, v, __ATOMIC_RELAXED, __HIP_MEMORY_SCOPE_AGENT);
}
template<bool LOC>
__device__ __forceinline__ void st16x(unsigned short* a, unsigned short v){
  if constexpr (LOC) *a = v;
  else __hip_atomic_store(a, v, __ATOMIC_RELAXED, __HIP_MEMORY_SCOPE_AGENT);
}
template<bool LOC>
__device__ __forceinline__ void st2x(float* a, float v0, float v1){
  if constexpr (LOC){ *(float2*)a = make_float2(v0, v1); }
  else {
    unsigned long long u = ((unsigned long long)__float_as_uint(v1) << 32)
                         | (unsigned long long)__float_as_uint(v0);
    __hip_atomic_store((unsigned long long*)a, u,
                       __ATOMIC_RELAXED, __HIP_MEMORY_SCOPE_AGENT);
  }
}
__device__ __forceinline__ void unpk8(const u32x4 w0, const u32x4 w1, bf16x8& hi, bf16x8& lo){
#pragma unroll
  for (int j = 0; j < 4; ++j){
    hi[j]   = (short)(w0[j] & 0xffffu); lo[j]   = (short)(w0[j] >> 16);
    hi[4+j] = (short)(w1[j] & 0xffffu); lo[4+j] = (short)(w1[j] >> 16);
  }
}

struct Params {
  const float *x, *Wt, *Wsn, *Wip, *bip, *U, *Vlr, *bias, *WQ, *WK, *WV, *Wout, *bout;
  float *out0, *hid, *ain, *acm, *aww;
  unsigned short *WVs, *WVl, *WQKhi, *WQKlo, *Wfshi, *Wfslo, *Wins, *Wouthi, *Woutlo;
  unsigned *Hpk;
  unsigned short *Qs16, *Ks16;
  float *Apart;
  unsigned *bar;
};

// ---------------- prep: fold W_in @ Wip (fp32), swizzle into B-frag layout (hi/lo)
__global__ void prep_fold(Params p){
  int bid = blockIdx.x; int d = threadIdx.x;   // 256 blocks x 256 threads
  int m, i;
  if (bid < 32)       { m = 0; i = bid; }
  else if (bid < 64)  { m = 1; i = bid - 32; }
  else if (bid < 160) { m = 2; i = bid - 64; }
  else                { m = 3; i = bid - 160; }
  const float* wrow = (m < 2) ? (p.Wt + (m*32 + i)*256) : (p.Wsn + ((m-2)*96 + i)*256);
  const float* wip  = p.Wip + (long)m*256*256;
  float acc = 0.f;
  for (int h = 0; h < 256; ++h) acc += wrow[h] * wip[h*256 + d];
  int kt = i >> 5, j = i & 7, lane = ((i >> 3) & 3)*16 + (d & 15), nt = d >> 4;
  long off = (((long)(m*3 + kt)*16 + nt)*64 + lane)*8 + j;
  unsigned short hi = f2bf(acc);
  p.Wfshi[off] = hi;
  p.Wfslo[off] = f2bf(acc - bf2f(hi));
  p.Wins[off]  = f2bf(wrow[d]);
}

// ---------------- prep: swizzle W_V (hi+lo), W_Q|W_K, Wout^T into B-frag layouts
__global__ void prep_swz(Params p){
  int bid = blockIdx.x, tid = threadIdx.x;     // 241 blocks x 512 threads
  if (bid < 192){
    int a = bid/48, n = (bid/8)%6, kt = bid%8;
    const float* src = p.WV + ((long)(a*6+n)*256 + kt*32)*256;
    for (int e = tid; e < 8192; e += 512){
      int hl = e >> 8, d = e & 255;            // h = kt*32+hl
      float w = src[hl*256 + d];
      int dsx = d >> 5, dt = (d >> 4) & 1, dcol = d & 15;
      int lane = ((hl>>3)&3)*16 + dcol, j = hl & 7;
      long off = (((((long)(a*8+dsx)*6 + n)*8 + kt)*2 + dt)*64 + lane)*8 + j;
      unsigned short hi = f2bf(w);
      p.WVs[off] = hi;
      p.WVl[off] = f2bf(w - bf2f(hi));
    }
  } else if (bid < 240){
    int q2 = bid - 192; int m = q2/8, kt = q2%8;
    for (int e = tid; e < 4096; e += 512){
      int hl = e >> 7, c = e & 127;            // cols: [Q a0..3 | K a0..3] x16
      int isK = c >> 6, a = (c>>4)&3, q = c&15;
      const float* W = isK ? p.WK : p.WQ;
      float w = W[((long)(a*6+m)*256 + kt*32 + hl)*16 + q];
      int lane = ((hl>>3)&3)*16 + q, j = hl&7, nt = c>>4;
      long off = (((long)(m*8+kt)*8 + nt)*512) + (long)lane*8 + j;
      unsigned short hi = f2bf(w);
      p.WQKhi[off] = hi; p.WQKlo[off] = f2bf(w - bf2f(hi));
    }
  } else {
    for (int e = tid; e < 32768; e += 512){
      int o = e >> 9, kk = e & 511;
      float w = p.Wout[o*512 + kk];
      int kt = kk>>5, j = kk&7, lane = (((kk>>3)&3)<<4) + (o&15), nt = o>>4;
      long off = ((long)(kt*4+nt)*512) + lane*8 + j;
      unsigned short hi = f2bf(w);
      p.Wouthi[off] = hi; p.Woutlo[off] = f2bf(w - bf2f(hi));
    }
  }
}

// ---------------- per-group barrier (32 participants by construction)
template<bool LOC>
__device__ __forceinline__ void xbar(unsigned* bar, int grp, unsigned ep){
  __syncthreads();                 // drains vmcnt: block's stores are visible
  if (threadIdx.x == 0){
    unsigned old;
    if constexpr (LOC)
      old = __hip_atomic_fetch_add(bar + 512 + grp*32, 1u,
              __ATOMIC_RELAXED, __HIP_MEMORY_SCOPE_WORKGROUP);
    else
      old = __hip_atomic_fetch_add(bar + 512 + grp*32, 1u,
              __ATOMIC_RELAXED, __HIP_MEMORY_SCOPE_AGENT);
    if (old == ep * 32u - 1u){
      __hip_atomic_store(bar + 768 + grp*32, ep,
                         __ATOMIC_RELAXED, __HIP_MEMORY_SCOPE_AGENT);
    } else {
      while (__hip_atomic_load(bar + 768 + grp*32,
               __ATOMIC_RELAXED, __HIP_MEMORY_SCOPE_AGENT) < ep)
        __builtin_amdgcn_s_sleep(2);
    }
  }
  __syncthreads();
}

// ---------------- the 128-step loop, templated on XCD-locality
template<bool LOC>
__device__ void run_steps(const Params& p, char* smem, int grp, int rank){
  unsigned short* ldsW = (unsigned short*)smem;            // 98304  W_V-hi frags
  float* awPrevS = (float*)(smem + 98304);                 // 4608   aw(t-1) [32][36]
  // X zone (aliases Y zone):
  unsigned short* xs  = (unsigned short*)(smem + 102912);  // 2048
  unsigned short* xsl = (unsigned short*)(smem + 104960);  // 2048
  unsigned short* hs  = (unsigned short*)(smem + 107008);  // 4096
  unsigned short* hsl = (unsigned short*)(smem + 111104);  // 4096
  float* inpS = (float*)(smem + 115200);                   // 8192
  float* hcS  = (float*)(smem + 123392);                   // 8192
  float* rS   = (float*)(smem + 131584);                   // 512
  float* accS = (float*)(smem + 132096);                   // 8192
  // Y zone:
  float* VcS  = (float*)(smem + 102912);                   // 24576  [6][32][32]
  float* awS  = (float*)(smem + 127488);                   // 4608   [32][36]
  float* QKs  = (float*)(smem + 132096);                   // 24576  [32][192]

  const int tid = threadIdx.x;
  const int lane = tid & 63, wv = tid >> 6;
  const int d = tid & 255, g = tid >> 8;
  const int rows0 = grp * 32;
  // X role
  const int xm = rank % 6, xrc = rank / 6;                 // valid when rank<24
  const int rowX = rows0 + xrc*8;
  // Y role
  const int ya = rank >> 3, yds = rank & 7;

  float hin[4] = {0.f, 0.f, 0.f, 0.f};
  float hc[4];
  unsigned ep = 0;

  for (int t = 0; t <= T_STEPS; ++t){
    // ================= X phase =================
    if (rank < 24){
      if (t > 0){
        // gather A_comm = sum_a A_part[a][xm][b][:]
        {
          int r = tid >> 6, dq = tid & 63;
          int b = rowX + r;
          const float* ap = p.Apart + ((long)xm*256 + b)*256 + dq*4;
          u32x4 v0, v1, v2, v3;
          ld4x<LOC>(ap,           v0);
          ld4x<LOC>(ap +  393216, v1);
          ld4x<LOC>(ap +  786432, v2);
          ld4x<LOC>(ap + 1179648, v3);
          vmwait();
          f32x4 s;
#pragma unroll
          for (int c = 0; c < 4; ++c)
            s[c] = __uint_as_float(v0[c]) + __uint_as_float(v1[c])
                 + __uint_as_float(v2[c]) + __uint_as_float(v3[c]);
          *(f32x4*)&accS[r*256 + dq*4] = s;
        }
        __syncthreads();
#pragma unroll
        for (int k = 0; k < 4; ++k){
          int bl = g*4 + k; int b = rowX + bl;
          float acc = accS[bl*256 + d];
          float hcm = hin[k] + acc;
          hc[k] = hcm;
          long o = ((long)(b*T_STEPS + (t-1))*6 + xm)*256 + d;
          if (xm >= 4) stf<LOC>(&p.hid[o], hcm);     // read by out-proj duty
          else __builtin_nontemporal_store(hcm, &p.hid[o]);
          __builtin_nontemporal_store(acc, &p.acm[o]);
        }
      } else {
        hc[0] = hc[1] = hc[2] = hc[3] = 0.f;
      }

      if (t < T_STEPS){
        if (xm >= 4){
#pragma unroll
          for (int k = 0; k < 4; ++k){
            int b = rowX + g*4 + k;
            __builtin_nontemporal_store(0.f, &p.ain[((long)(b*T_STEPS + t)*6 + xm)*256 + d]);
          }
        }
        // stage x (bf16 hi/lo, xor-swizzled rows)
#pragma unroll
        for (int h2 = 0; h2 < 2; ++h2){
          int i0 = tid + h2*512;
          int r0 = i0 >> 7, c0 = i0 & 127;
          float v = p.x[((long)(rowX + r0)*T_STEPS + t)*128 + c0];
          unsigned short hi = f2bf(v);
          int idx = r0*128 + (c0 ^ ((r0&7)<<3));
          xs[idx] = hi; xsl[idx] = f2bf(v - bf2f(hi));
        }
        __syncthreads();
        // A_in (single bf16) + inp (emu-fp32) via MFMA (modules 0..3)
        if (xm < 4){
          int nkt = (xm < 2) ? 1 : 3;
          int kbase = (xm < 2) ? 96 : 0;
#pragma unroll
          for (int half = 0; half < 2; ++half){
            int nt = wv*2 + half;
            f32x4 cin = {0.f,0.f,0.f,0.f}, cf = {0.f,0.f,0.f,0.f};
            for (int kt = 0; kt < nkt; ++kt){
              bf16x8 ah = bzero8(), al = bzero8();
              int r = lane & 15;
              if (r < 8){
                int kk = kbase + kt*32 + ((lane>>4)<<3);
                int idx = r*128 + (kk ^ ((r&7)<<3));
                ah = *(const bf16x8*)&xs[idx];
                al = *(const bf16x8*)&xsl[idx];
              }
              long boff = (((long)(xm*3 + kt)*16 + nt)*64 + lane)*8;
              bf16x8 bi = *(const bf16x8*)(p.Wins  + boff);
              bf16x8 bh = *(const bf16x8*)(p.Wfshi + boff);
              bf16x8 bl = *(const bf16x8*)(p.Wfslo + boff);
              cin = __builtin_amdgcn_mfma_f32_16x16x32_bf16(ah, bi, cin, 0, 0, 0);
              cf  = __builtin_amdgcn_mfma_f32_16x16x32_bf16(ah, bh, cf , 0, 0, 0);
              cf  = __builtin_amdgcn_mfma_f32_16x16x32_bf16(al, bh, cf , 0, 0, 0);
              cf  = __builtin_amdgcn_mfma_f32_16x16x32_bf16(ah, bl, cf , 0, 0, 0);
            }
            int col = nt*16 + (lane & 15);
#pragma unroll
            for (int i = 0; i < 4; ++i){
              int r = ((lane>>4)<<2) + i;
              if (r < 8){
                int b = rowX + r;
                __builtin_nontemporal_store(cin[i], &p.ain[((long)(b*T_STEPS + t)*6 + xm)*256 + col]);
                inpS[r*256 + col] = cf[i];
              }
            }
          }
        }
        __syncthreads();
#pragma unroll
        for (int k = 0; k < 4; ++k) hcS[(g*4 + k)*256 + d] = hc[k];
        __syncthreads();
        // rec part 1: r[b][q] = sum_h Hc[b][h] U[m][h][q]  (fp32)
        {
          int bl = tid >> 6, q = (tid >> 2) & 15, part = tid & 3;
          const float* up = p.U + (long)xm*256*16 + q;
          float s = 0.f;
          int d0 = part*64;
          for (int dd = 0; dd < 64; ++dd) s += hcS[bl*256 + d0 + dd] * up[(d0 + dd)*16];
          s += __shfl_down(s, 1);
          s += __shfl_down(s, 2);
          if (part == 0) rS[bl*16 + q] = s;
        }
        __syncthreads();
        // H_in = tanh(inp + rec + bip + bias); stash packed bf16 hi|lo
        // Hpk layout: [m][kt=8][b=256][32]  (dense 2KB wave windows in Y)
#pragma unroll
        for (int k = 0; k < 4; ++k){
          int bl = g*4 + k;
          float pre = p.bip[xm*256 + d] + p.bias[xm*256 + d];
          if (xm < 4) pre += inpS[bl*256 + d];
          const float* vl = p.Vlr + (long)xm*16*256 + d;
#pragma unroll
          for (int q = 0; q < 16; ++q) pre += rS[bl*16 + q] * vl[q*256];
          float h = tanhf(pre);
          hin[k] = h;
          unsigned short hi = f2bf(h);
          unsigned short lo = f2bf(h - bf2f(hi));
          int b = rowX + bl;
          stu<LOC>(&p.Hpk[(((long)(xm*8 + (d>>5))*256 + b)*32) + (d & 31)],
                   (unsigned)hi | ((unsigned)lo << 16));
          int idx = bl*256 + (d ^ ((bl&7)<<3));
          hs[idx] = hi; hsl[idx] = lo;
        }
        __syncthreads();
        // Q/K via MFMA (emu-fp32): cols = [Q a0..3 | K a0..3] x 16; store bf16
        {
          int nt = wv;
          f32x4 c = {0.f,0.f,0.f,0.f};
#pragma unroll
          for (int kt = 0; kt < 8; ++kt){
            bf16x8 ah = bzero8(), al = bzero8();
            int r = lane & 15;
            if (r < 8){
              int kk = kt*32 + ((lane>>4)<<3);
              int idx = r*256 + (kk ^ ((r&7)<<3));
              ah = *(const bf16x8*)&hs[idx];
              al = *(const bf16x8*)&hsl[idx];
            }
            long bo = (((long)(xm*8 + kt)*8 + nt)*64 + lane)*8;
            bf16x8 bh = *(const bf16x8*)(p.WQKhi + bo);
            bf16x8 bl = *(const bf16x8*)(p.WQKlo + bo);
            c = __builtin_amdgcn_mfma_f32_16x16x32_bf16(ah, bh, c, 0, 0, 0);
            c = __builtin_amdgcn_mfma_f32_16x16x32_bf16(al, bh, c, 0, 0, 0);
            c = __builtin_amdgcn_mfma_f32_16x16x32_bf16(ah, bl, c, 0, 0, 0);
          }
          unsigned short* dst = (nt < 4) ? p.Qs16 : p.Ks16;
          int a2 = nt & 3, q = lane & 15;
#pragma unroll
          for (int i = 0; i < 4; ++i){
            int r = ((lane>>4)<<2) + i;
            if (r < 8){
              int b = rowX + r;
              st16x<LOC>(&dst[((long)(a2*256 + b)*6 + xm)*16 + q], f2bf(c[i]));
            }
          }
        }
      }
    }

    xbar<LOC>(p.bar, grp, ++ep);

    // ================= Y phase =================
    if (t < T_STEPS){
      if (wv < 6){
        // Vc = H_in @ W_V[a][n], emu-fp32 (Ah*Bh + Al*Bh + Ah*Bl)
        int n = wv;
        f32x4 C00={0,0,0,0}, C01={0,0,0,0}, C10={0,0,0,0}, C11={0,0,0,0};
        int b0 = rows0 + (lane & 15);
        int hof = (lane >> 4) << 3;
        const unsigned short* wlBase = p.WVl + (long)rank*49152;
#pragma unroll
        for (int kt = 0; kt < 8; ++kt){
          const unsigned* h00 = p.Hpk + (((long)(n*8 + kt)*256 + b0)*32) + hof;
          u32x4 q0, q1, q2, q3;
          ld4x<LOC>(h00,       q0); ld4x<LOC>(h00 + 4,   q1);
          ld4x<LOC>(h00 + 512, q2); ld4x<LOC>(h00 + 516, q3);   // row b0+16
          vmwait();
          bf16x8 Ah0, Al0, Ah1, Al1;
          unpk8(q0, q1, Ah0, Al0); unpk8(q2, q3, Ah1, Al1);
          bf16x8 B0 = *(const bf16x8*)&ldsW[((n*8 + kt)*2 + 0)*512 + lane*8];
          bf16x8 B1 = *(const bf16x8*)&ldsW[((n*8 + kt)*2 + 1)*512 + lane*8];
          bf16x8 L0 = *(const bf16x8*)(wlBase + (((n*8 + kt)*2 + 0)*512 + lane*8));
          bf16x8 L1 = *(const bf16x8*)(wlBase + (((n*8 + kt)*2 + 1)*512 + lane*8));
          C00 = __builtin_amdgcn_mfma_f32_16x16x32_bf16(Ah0, B0, C00, 0, 0, 0);
          C00 = __builtin_amdgcn_mfma_f32_16x16x32_bf16(Al0, B0, C00, 0, 0, 0);
          C00 = __builtin_amdgcn_mfma_f32_16x16x32_bf16(Ah0, L0, C00, 0, 0, 0);
          C01 = __builtin_amdgcn_mfma_f32_16x16x32_bf16(Ah0, B1, C01, 0, 0, 0);
          C01 = __builtin_amdgcn_mfma_f32_16x16x32_bf16(Al0, B1, C01, 0, 0, 0);
          C01 = __builtin_amdgcn_mfma_f32_16x16x32_bf16(Ah0, L1, C01, 0, 0, 0);
          C10 = __builtin_amdgcn_mfma_f32_16x16x32_bf16(Ah1, B0, C10, 0, 0, 0);
          C10 = __builtin_amdgcn_mfma_f32_16x16x32_bf16(Al1, B0, C10, 0, 0, 0);
          C10 = __builtin_amdgcn_mfma_f32_16x16x32_bf16(Ah1, L0, C10, 0, 0, 0);
          C11 = __builtin_amdgcn_mfma_f32_16x16x32_bf16(Ah1, B1, C11, 0, 0, 0);
          C11 = __builtin_amdgcn_mfma_f32_16x16x32_bf16(Al1, B1, C11, 0, 0, 0);
          C11 = __builtin_amdgcn_mfma_f32_16x16x32_bf16(Ah1, L1, C11, 0, 0, 0);
        }
        int col = lane & 15, rb = (lane >> 4) << 2;
#pragma unroll
        for (int i = 0; i < 4; ++i){
          VcS[n*1024 + (rb+i)*32 + col]         = C00[i];
          VcS[n*1024 + (rb+i)*32 + 16 + col]    = C01[i];
          VcS[n*1024 + (16+rb+i)*32 + col]      = C10[i];
          VcS[n*1024 + (16+rb+i)*32 + 16 + col] = C11[i];
        }
      } else {
        // duty waves 6,7: attention weights for head ya, 32 rows
        int t2 = tid - 384, r = t2 >> 2, q4 = t2 & 3;
        int b = rows0 + r;
        const unsigned short* qrow = p.Qs16 + (long)(ya*256 + b)*96;
        const unsigned short* krow = p.Ks16 + (long)(ya*256 + b)*96;
        u32x4 tv[6];
#pragma unroll
        for (int s = 0; s < 6; ++s){
          int e0 = q4*48 + s*8;
          const unsigned short* src = (e0 < 96) ? (qrow + e0) : (krow + e0 - 96);
          ld4x<LOC>(src, tv[s]);
        }
        vmwait();
#pragma unroll
        for (int s = 0; s < 6; ++s){
          int e0 = q4*48 + s*8;
#pragma unroll
          for (int j = 0; j < 4; ++j){
            unsigned w = tv[s][j];
            QKs[r*192 + e0 + j*2]     = bf2f((unsigned short)(w & 0xffffu));
            QKs[r*192 + e0 + j*2 + 1] = bf2f((unsigned short)(w >> 16));
          }
        }
        asm volatile("s_waitcnt lgkmcnt(0)" ::: "memory");
        __builtin_amdgcn_sched_barrier(0);
#pragma unroll
        for (int jj = 0; jj < 9; ++jj){
          int mn = q4*9 + jj, m = mn/6, n2 = mn - m*6;
          float dot = 0.f;
#pragma unroll
          for (int q = 0; q < 16; ++q)
            dot += QKs[r*192 + m*16 + q] * QKs[r*192 + 96 + n2*16 + q];
          float s = 1.f/(1.f + expf(-dot*0.25f));
          if (t > 0) s = 0.5f*s + 0.5f*awPrevS[r*36 + mn];
          awPrevS[r*36 + mn] = s;
          awS[r*36 + mn] = s;
          if (yds == 0)
            __builtin_nontemporal_store(s, &p.aww[(((long)ya*T_STEPS + t)*256 + b)*36 + mn]);
        }
      }
      __syncthreads();
      // contraction over n: A_part[a][m][b][yds*32+d] = sum_n aw[m,n] * Vc[n][b][d]
      {
        int b = tid >> 4, i2 = tid & 15, d0 = i2*2;
        float s0[6], s1[6];
#pragma unroll
        for (int m = 0; m < 6; ++m){ s0[m] = 0.f; s1[m] = 0.f; }
#pragma unroll
        for (int n = 0; n < 6; ++n){
          float v0 = VcS[n*1024 + b*32 + d0];
          float v1 = VcS[n*1024 + b*32 + d0 + 1];
#pragma unroll
          for (int m = 0; m < 6; ++m){
            float w = awS[b*36 + m*6 + n];
            s0[m] += w*v0; s1[m] += w*v1;
          }
        }
#pragma unroll
        for (int m = 0; m < 6; ++m)
          st2x<LOC>(p.Apart + (((long)ya*6 + m)*256 + rows0 + b)*256 + yds*32 + d0,
                    s0[m], s1[m]);
      }
    }
    // out-proj duty (t-1): yds==7 blocks, waves 6,7
    if (t > 0 && yds == 7 && wv >= 6){
      int job = ya*2 + (wv - 6);               // 0..7
      int rt = job >> 2, ot = job & 3;
      f32x4 c = {0.f,0.f,0.f,0.f};
      for (int kt = 0; kt < 16; ++kt){
        int b = rows0 + rt*16 + (lane & 15);
        int kk = kt*32 + ((lane>>4)<<3);
        int m45 = kk >> 8, dd = kk & 255;
        const float* hp = p.hid + ((long)(b*T_STEPS + (t-1))*6 + 4 + m45)*256 + dd;
        u32x4 u0, u1;
        ld4x<LOC>(hp, u0); ld4x<LOC>(hp + 4, u1);
        vmwait();
        bf16x8 ah, al;
#pragma unroll
        for (int j = 0; j < 4; ++j){
          float v0 = __uint_as_float(u0[j]);
          float v1 = __uint_as_float(u1[j]);
          unsigned short h0 = f2bf(v0), h1 = f2bf(v1);
          ah[j]   = (short)h0; al[j]   = (short)f2bf(v0 - bf2f(h0));
          ah[4+j] = (short)h1; al[4+j] = (short)f2bf(v1 - bf2f(h1));
        }
        bf16x8 bh = *(const bf16x8*)(p.Wouthi + ((long)(kt*4 + ot)*512 + lane*8));
        bf16x8 bl = *(const bf16x8*)(p.Woutlo + ((long)(kt*4 + ot)*512 + lane*8));
        c = __builtin_amdgcn_mfma_f32_16x16x32_bf16(ah, bh, c, 0, 0, 0);
        c = __builtin_amdgcn_mfma_f32_16x16x32_bf16(al, bh, c, 0, 0, 0);
        c = __builtin_amdgcn_mfma_f32_16x16x32_bf16(ah, bl, c, 0, 0, 0);
      }
      int o = ot*16 + (lane & 15);
      float bo = p.bout[o];
#pragma unroll
      for (int i = 0; i < 4; ++i){
        int b = rows0 + rt*16 + ((lane>>4)<<2) + i;
        __builtin_nontemporal_store(c[i] + bo, &p.out0[((long)b*T_STEPS + (t-1))*64 + o]);
      }
    }

    if (t < T_STEPS) xbar<LOC>(p.bar, grp, ++ep);
  }
}

// ---------------- main persistent kernel
__global__ __launch_bounds__(512) void rim_main(Params p){
  extern __shared__ char smem[];
  const int tid = threadIdx.x, bid = blockIdx.x;
  const int grp = bid & 7, rank = bid >> 3;

  // ---- load this block's W_V-hi slice (96 KB) into LDS, once ----
  {
    const unsigned short* src = p.WVs + (long)rank*49152;
#pragma unroll
    for (int it = 0; it < 12; ++it)
      ((int4*)smem)[it*512 + tid] = ((const int4*)src)[it*512 + tid];
  }

  // ---- one-time registration: publish physical XCC_ID, verify group uniformity
  unsigned xcc;
  asm volatile("s_getreg_b32 %0, hwreg(HW_REG_XCC_ID)" : "=s"(xcc));
  __shared__ int sLoc;
  __syncthreads();
  if (tid == 0){
    __hip_atomic_store(p.bar + 64 + bid, xcc & 7u,
                       __ATOMIC_RELAXED, __HIP_MEMORY_SCOPE_AGENT);
    unsigned old = __hip_atomic_fetch_add(p.bar, 1u,
                       __ATOMIC_RELAXED, __HIP_MEMORY_SCOPE_AGENT);
    if (old == (unsigned)NBLK - 1u){
      __hip_atomic_store(p.bar + 16, 1u, __ATOMIC_RELAXED, __HIP_MEMORY_SCOPE_AGENT);
    } else {
      while (__hip_atomic_load(p.bar + 16, __ATOMIC_RELAXED, __HIP_MEMORY_SCOPE_AGENT) < 1u)
        __builtin_amdgcn_s_sleep(2);
    }
    unsigned ref = __hip_atomic_load(p.bar + 64 + grp,
                       __ATOMIC_RELAXED, __HIP_MEMORY_SCOPE_AGENT);
    int ok = 1;
    for (int k = 1; k < 32; ++k){
      unsigned v = __hip_atomic_load(p.bar + 64 + grp + 8*k,
                       __ATOMIC_RELAXED, __HIP_MEMORY_SCOPE_AGENT);
      ok &= (v == ref);
    }
    sLoc = ok;
  }
  __syncthreads();

  if (sLoc) run_steps<true>(p, smem, grp, rank);
  else      run_steps<false>(p, smem, grp, rank);
}

extern "C" void kernel_launch(void* const* d_in, const int* in_sizes, int n_in,
                              void* d_out, int out_size, void* d_ws, size_t ws_size,
                              hipStream_t stream) {
  (void)in_sizes; (void)n_in; (void)out_size;
  if (ws_size < 16060416) return;

  Params p;
  p.x    = (const float*)d_in[0];
  p.Wt   = (const float*)d_in[1];
  p.Wsn  = (const float*)d_in[2];
  p.Wip  = (const float*)d_in[3];
  p.bip  = (const float*)d_in[4];
  p.U    = (const float*)d_in[5];
  p.Vlr  = (const float*)d_in[6];
  p.bias = (const float*)d_in[7];
  p.WQ   = (const float*)d_in[8];
  p.WK   = (const float*)d_in[9];
  p.WV   = (const float*)d_in[10];
  p.Wout = (const float*)d_in[11];
  p.bout = (const float*)d_in[12];

  float* out = (float*)d_out;
  p.out0 = out;                    // (B,T,O)
  p.hid  = out + 2097152;          // (B,T,M,H)
  p.ain  = out + 52428800;         // (B,T,M,H)
  p.acm  = out + 102760448;        // (B,T,M,H)
  p.aww  = out + 153092096;        // (NH,T,B,M,M)

  char* ws = (char*)d_ws;
  p.bar    = (unsigned*)ws;                         //        0     4096
  p.WVs    = (unsigned short*)(ws + 4096);          //  3145728
  p.WVl    = (unsigned short*)(ws + 3149824);       //  3145728
  p.WQKhi  = (unsigned short*)(ws + 6295552);       //   393216
  p.WQKlo  = (unsigned short*)(ws + 6688768);       //   393216
  p.Wfshi  = (unsigned short*)(ws + 7081984);       //   196608
  p.Wfslo  = (unsigned short*)(ws + 7278592);       //   196608
  p.Wins   = (unsigned short*)(ws + 7475200);       //   196608
  p.Wouthi = (unsigned short*)(ws + 7671808);       //    65536
  p.Woutlo = (unsigned short*)(ws + 7737344);       //    65536
  p.Hpk    = (unsigned*)(ws + 7802880);             //  1572864
  p.Qs16   = (unsigned short*)(ws + 9375744);       //   196608
  p.Ks16   = (unsigned short*)(ws + 9572352);       //   196608
  p.Apart  = (float*)(ws + 9768960);                //  6291456 -> 16060416

  hipMemsetAsync(d_ws, 0, 4096, stream);
  hipLaunchKernelGGL(prep_fold, dim3(256), dim3(256), 0, stream, p);
  hipLaunchKernelGGL(prep_swz,  dim3(241), dim3(512), 0, stream, p);

  hipFuncSetAttribute((const void*)rim_main,
                      hipFuncAttributeMaxDynamicSharedMemorySize, 156672);
  Params pArg = p;
  void* args[] = { &pArg };
  hipLaunchCooperativeKernel((const void*)rim_main, dim3(NBLK), dim3(512),
                             args, 156672, stream);
}